// Round 1
// baseline (3448.750 us; speedup 1.0000x reference)
//
#include <hip/hip_runtime.h>
#include <cmath>

// ---------------------------------------------------------------------------
// Decoder_1898375544952: STGCN decoder
//   h0 = x @ W_lin + b_lin                         [N,16]
//   h3 = relu(h0 @ Ws3 + mean_agg(h0) @ Wn3 + b3)  [N,32]
//   h2 = relu(h3 @ Ws2 + mean_agg(h3) @ Wn2 + b2)  [N,64]
//   out= sigm(h2 @ Ws1 + mean_agg(h2) @ Wn1 + b1)  [N,128]
// mean_agg(x)[d] = (sum_{e: dst[e]==d} x[src[e]]) / max(deg[d],1)
// ---------------------------------------------------------------------------

__global__ void deg_kernel(const int* __restrict__ dst, float* __restrict__ deg, int E) {
    int i = blockIdx.x * blockDim.x + threadIdx.x;
    if (i < E) atomicAdd(&deg[dst[i]], 1.0f);
}

// h0 = x @ W (16x16) + b
__global__ void lin16_kernel(const float* __restrict__ x, const float* __restrict__ W,
                             const float* __restrict__ b, float* __restrict__ h, int N) {
    __shared__ float sW[256];
    __shared__ float sb[16];
    sW[threadIdx.x] = W[threadIdx.x];          // blockDim.x == 256
    if (threadIdx.x < 16) sb[threadIdx.x] = b[threadIdx.x];
    __syncthreads();
    int n = blockIdx.x * blockDim.x + threadIdx.x;
    if (n >= N) return;
    const float4* xr = (const float4*)(x + (size_t)n * 16);
    float4 x0 = xr[0], x1 = xr[1], x2 = xr[2], x3 = xr[3];
    float xi[16] = {x0.x, x0.y, x0.z, x0.w, x1.x, x1.y, x1.z, x1.w,
                    x2.x, x2.y, x2.z, x2.w, x3.x, x3.y, x3.z, x3.w};
    float o[16];
#pragma unroll
    for (int j = 0; j < 16; j++) o[j] = sb[j];
#pragma unroll
    for (int k = 0; k < 16; k++) {
        float xv = xi[k];
#pragma unroll
        for (int j = 0; j < 16; j++) o[j] += xv * sW[k * 16 + j];
    }
    float4* hr = (float4*)(h + (size_t)n * 16);
    hr[0] = make_float4(o[0], o[1], o[2], o[3]);
    hr[1] = make_float4(o[4], o[5], o[6], o[7]);
    hr[2] = make_float4(o[8], o[9], o[10], o[11]);
    hr[3] = make_float4(o[12], o[13], o[14], o[15]);
}

// agg[dst] += h[src], one thread per (edge, 4-channel group)
template <int C>
__global__ void scatter_kernel(const int* __restrict__ src, const int* __restrict__ dst,
                               const float* __restrict__ h, float* __restrict__ agg, int E) {
    constexpr int GP = C / 4;
    int t = blockIdx.x * blockDim.x + threadIdx.x;
    int total = E * GP;
    if (t >= total) return;
    int e = t / GP;
    int g = t - e * GP;
    int s = src[e];
    int d = dst[e];
    float4 v = *(const float4*)(h + (size_t)s * C + g * 4);
    float* p = agg + (size_t)d * C + g * 4;
    atomicAdd(p + 0, v.x);
    atomicAdd(p + 1, v.y);
    atomicAdd(p + 2, v.z);
    atomicAdd(p + 3, v.w);
}

// out[:, j0:j0+CO_TILE] = act(h @ Ws + (agg/deg) @ Wn + b), weights in LDS.
// ACT: 0 = relu, 1 = sigmoid
template <int CI, int CO, int CO_TILE, int ACT>
__global__ void combine_kernel(const float* __restrict__ h, const float* __restrict__ agg,
                               const float* __restrict__ deg,
                               const float* __restrict__ Ws, const float* __restrict__ Wn,
                               const float* __restrict__ bias,
                               float* __restrict__ out, int N) {
    constexpr int GP = CO_TILE / 4;
    extern __shared__ float lds[];
    float* sWs = lds;                // [CI][CO_TILE]
    float* sWn = lds + CI * CO_TILE; // [CI][CO_TILE]
    const int j0 = blockIdx.y * CO_TILE;
    for (int i = threadIdx.x; i < CI * CO_TILE; i += blockDim.x) {
        int k = i / CO_TILE;
        int j = i - k * CO_TILE;
        sWs[i] = Ws[(size_t)k * CO + j0 + j];
        sWn[i] = Wn[(size_t)k * CO + j0 + j];
    }
    __syncthreads();

    int t = blockIdx.x * blockDim.x + threadIdx.x;
    int total = N * GP;
    if (t >= total) return;
    int n = t / GP;
    int g = t - n * GP;

    float inv = 1.0f / fmaxf(deg[n], 1.0f);
    float4 acc = *(const float4*)(bias + j0 + g * 4);
    const float* hr = h + (size_t)n * CI;
    const float* ar = agg + (size_t)n * CI;
#pragma unroll
    for (int k = 0; k < CI; k++) {
        float hv = hr[k];
        float av = ar[k] * inv;
        float4 ws = *(const float4*)(sWs + k * CO_TILE + g * 4);
        float4 wn = *(const float4*)(sWn + k * CO_TILE + g * 4);
        acc.x += hv * ws.x + av * wn.x;
        acc.y += hv * ws.y + av * wn.y;
        acc.z += hv * ws.z + av * wn.z;
        acc.w += hv * ws.w + av * wn.w;
    }
    if (ACT == 0) {
        acc.x = fmaxf(acc.x, 0.0f);
        acc.y = fmaxf(acc.y, 0.0f);
        acc.z = fmaxf(acc.z, 0.0f);
        acc.w = fmaxf(acc.w, 0.0f);
    } else {
        acc.x = 1.0f / (1.0f + __expf(-acc.x));
        acc.y = 1.0f / (1.0f + __expf(-acc.y));
        acc.z = 1.0f / (1.0f + __expf(-acc.z));
        acc.w = 1.0f / (1.0f + __expf(-acc.w));
    }
    *(float4*)(out + (size_t)n * CO + j0 + g * 4) = acc;
}

extern "C" void kernel_launch(void* const* d_in, const int* in_sizes, int n_in,
                              void* d_out, int out_size, void* d_ws, size_t ws_size,
                              hipStream_t stream) {
    const float* x     = (const float*)d_in[0];
    const int*   ei    = (const int*)d_in[1];
    // d_in[2]: batch (unused)
    const float* W_lin = (const float*)d_in[3];
    const float* b_lin = (const float*)d_in[4];
    const float* Ws3   = (const float*)d_in[5];
    const float* Wn3   = (const float*)d_in[6];
    const float* b3    = (const float*)d_in[7];
    const float* Ws2   = (const float*)d_in[8];
    const float* Wn2   = (const float*)d_in[9];
    const float* b2    = (const float*)d_in[10];
    const float* Ws1   = (const float*)d_in[11];
    const float* Wn1   = (const float*)d_in[12];
    const float* b1    = (const float*)d_in[13];
    float* out = (float*)d_out;

    const int N = in_sizes[0] / 16;
    const int E = in_sizes[1] / 2;
    const int* src = ei;
    const int* dst = ei + E;

    // Workspace layout (bytes, with reuse; peak = N*516 ~= 64.5 MB):
    //   deg   : [0,        N*4)
    //   h0    : [N*4,      N*68)    N*16 f32
    //   agg16 : [N*68,     N*132)   N*16 f32
    //   h3    : [N*132,    N*260)   N*32 f32
    //   agg32 : reuse [N*4, N*132)  (h0+agg16 dead)
    //   h2    : [N*260,    N*516)   N*64 f32
    //   agg64 : reuse [N*4, N*260)  (h3 dead)
    char* ws = (char*)d_ws;
    float* deg   = (float*)(ws);
    float* h0    = (float*)(ws + (size_t)N * 4);
    float* agg16 = (float*)(ws + (size_t)N * 68);
    float* h3    = (float*)(ws + (size_t)N * 132);
    float* agg32 = h0;
    float* h2    = (float*)(ws + (size_t)N * 260);
    float* agg64 = h0;

    const int BLK = 256;

    // degree (shared by all 3 blocks)
    hipMemsetAsync(deg, 0, (size_t)N * 4, stream);
    deg_kernel<<<(E + BLK - 1) / BLK, BLK, 0, stream>>>(dst, deg, E);

    // h0 = x @ W_lin + b_lin
    lin16_kernel<<<(N + BLK - 1) / BLK, BLK, 0, stream>>>(x, W_lin, b_lin, h0, N);

    // block3: 16 -> 32, relu
    hipMemsetAsync(agg16, 0, (size_t)N * 64, stream);
    scatter_kernel<16><<<((size_t)E * 4 + BLK - 1) / BLK, BLK, 0, stream>>>(src, dst, h0, agg16, E);
    {
        dim3 grid((N * 8 + BLK - 1) / BLK, 1);
        size_t shmem = 2 * 16 * 32 * sizeof(float);
        combine_kernel<16, 32, 32, 0><<<grid, BLK, shmem, stream>>>(h0, agg16, deg, Ws3, Wn3, b3, h3, N);
    }

    // block2: 32 -> 64, relu
    hipMemsetAsync(agg32, 0, (size_t)N * 128, stream);
    scatter_kernel<32><<<((size_t)E * 8 + BLK - 1) / BLK, BLK, 0, stream>>>(src, dst, h3, agg32, E);
    {
        dim3 grid((N * 16 + BLK - 1) / BLK, 1);
        size_t shmem = 2 * 32 * 64 * sizeof(float);
        combine_kernel<32, 64, 64, 0><<<grid, BLK, shmem, stream>>>(h3, agg32, deg, Ws2, Wn2, b2, h2, N);
    }

    // block1: 64 -> 128, sigmoid -> d_out
    hipMemsetAsync(agg64, 0, (size_t)N * 256, stream);
    scatter_kernel<64><<<((size_t)E * 16 + BLK - 1) / BLK, BLK, 0, stream>>>(src, dst, h2, agg64, E);
    {
        dim3 grid((N * 16 + BLK - 1) / BLK, 2);
        size_t shmem = 2 * 64 * 64 * sizeof(float);
        combine_kernel<64, 128, 64, 1><<<grid, BLK, shmem, stream>>>(h2, agg64, deg, Ws1, Wn1, b1, out, N);
    }
}

// Round 2
// 731.936 us; speedup vs baseline: 4.7118x; 4.7118x over previous
//
#include <hip/hip_runtime.h>
#include <cmath>

// ---------------------------------------------------------------------------
// Decoder_1898375544952: STGCN decoder (CSR-gather version, no fp atomics)
//   h0 = x @ W_lin + b_lin                         [N,16]
//   h3 = relu(h0 @ Ws3 + mean_agg(h0) @ Wn3 + b3)  [N,32]
//   h2 = relu(h3 @ Ws2 + mean_agg(h3) @ Wn2 + b2)  [N,64]
//   out= sigm(h2 @ Ws1 + mean_agg(h2) @ Wn1 + b1)  [N,128]
// mean_agg(x)[d] = (sum_{e: dst[e]==d} x[src[e]]) / max(deg[d],1)
//
// R1 showed fp32 atomic scatter = 2 GB write-through per layer (atomics punch
// through per-XCD L2). R2: build CSR by dst once (int atomics only), then
// aggregate with deterministic gathers. deg derived from row_ptr.
// ---------------------------------------------------------------------------

__global__ void hist_kernel(const int* __restrict__ dst, int* __restrict__ cnt, int E) {
    int i = blockIdx.x * blockDim.x + threadIdx.x;
    if (i < E) atomicAdd(&cnt[dst[i]], 1);
}

// Block-level exclusive scan of cnt -> row_ptr (partial), block sums -> bsum.
// Requires N % 256 == 0.
__global__ void scan1_kernel(const int* __restrict__ cnt, int* __restrict__ row_ptr,
                             int* __restrict__ bsum) {
    __shared__ int s[256];
    int i = blockIdx.x * 256 + threadIdx.x;
    int v = cnt[i];
    s[threadIdx.x] = v;
    __syncthreads();
    for (int off = 1; off < 256; off <<= 1) {
        int t = (threadIdx.x >= off) ? s[threadIdx.x - off] : 0;
        __syncthreads();
        s[threadIdx.x] += t;
        __syncthreads();
    }
    row_ptr[i] = s[threadIdx.x] - v;   // exclusive within block
    if (threadIdx.x == 255) bsum[blockIdx.x] = s[255];
}

// Exclusive scan of bsum[NB] in place, single block of NB threads (NB<=1024).
__global__ void scan2_kernel(int* __restrict__ bsum, int NB) {
    extern __shared__ int s2[];
    int v = (threadIdx.x < NB) ? bsum[threadIdx.x] : 0;
    s2[threadIdx.x] = v;
    __syncthreads();
    for (int off = 1; off < NB; off <<= 1) {
        int t = (threadIdx.x >= off) ? s2[threadIdx.x - off] : 0;
        __syncthreads();
        s2[threadIdx.x] += t;
        __syncthreads();
    }
    if (threadIdx.x < NB) bsum[threadIdx.x] = s2[threadIdx.x] - v;
}

__global__ void scan3_kernel(int* __restrict__ row_ptr, const int* __restrict__ bsum,
                             int N, int E) {
    int i = blockIdx.x * 256 + threadIdx.x;
    row_ptr[i] += bsum[blockIdx.x];
    if (i == 0) row_ptr[N] = E;
}

__global__ void fill_kernel(const int* __restrict__ src, const int* __restrict__ dst,
                            const int* __restrict__ row_ptr, int* __restrict__ cursor,
                            int* __restrict__ csr_src, int E) {
    int i = blockIdx.x * blockDim.x + threadIdx.x;
    if (i >= E) return;
    int d = dst[i];
    int p = atomicAdd(&cursor[d], 1);
    csr_src[row_ptr[d] + p] = src[i];
}

// h0 = x @ W (16x16) + b
__global__ void lin16_kernel(const float* __restrict__ x, const float* __restrict__ W,
                             const float* __restrict__ b, float* __restrict__ h, int N) {
    __shared__ float sW[256];
    __shared__ float sb[16];
    sW[threadIdx.x] = W[threadIdx.x];          // blockDim.x == 256
    if (threadIdx.x < 16) sb[threadIdx.x] = b[threadIdx.x];
    __syncthreads();
    int n = blockIdx.x * blockDim.x + threadIdx.x;
    if (n >= N) return;
    const float4* xr = (const float4*)(x + (size_t)n * 16);
    float4 x0 = xr[0], x1 = xr[1], x2 = xr[2], x3 = xr[3];
    float xi[16] = {x0.x, x0.y, x0.z, x0.w, x1.x, x1.y, x1.z, x1.w,
                    x2.x, x2.y, x2.z, x2.w, x3.x, x3.y, x3.z, x3.w};
    float o[16];
#pragma unroll
    for (int j = 0; j < 16; j++) o[j] = sb[j];
#pragma unroll
    for (int k = 0; k < 16; k++) {
        float xv = xi[k];
#pragma unroll
        for (int j = 0; j < 16; j++) o[j] += xv * sW[k * 16 + j];
    }
    float4* hr = (float4*)(h + (size_t)n * 16);
    hr[0] = make_float4(o[0], o[1], o[2], o[3]);
    hr[1] = make_float4(o[4], o[5], o[6], o[7]);
    hr[2] = make_float4(o[8], o[9], o[10], o[11]);
    hr[3] = make_float4(o[12], o[13], o[14], o[15]);
}

// agg[n][g*4..] = sum over CSR neighbors of h[src][g*4..]; pure gather.
template <int C>
__global__ void gather_kernel(const int* __restrict__ row_ptr, const int* __restrict__ csr_src,
                              const float* __restrict__ h, float* __restrict__ agg, int N) {
    constexpr int GP = C / 4;
    int t = blockIdx.x * blockDim.x + threadIdx.x;
    int total = N * GP;
    if (t >= total) return;
    int n = t / GP;
    int g = t - n * GP;
    int beg = row_ptr[n];
    int end = row_ptr[n + 1];
    float4 s = make_float4(0.f, 0.f, 0.f, 0.f);
    for (int j = beg; j < end; ++j) {
        int sn = csr_src[j];
        float4 v = *(const float4*)(h + (size_t)sn * C + g * 4);
        s.x += v.x; s.y += v.y; s.z += v.z; s.w += v.w;
    }
    *(float4*)(agg + (size_t)n * C + g * 4) = s;
}

// out[:, j0:j0+CO_TILE] = act(h @ Ws + (agg/deg) @ Wn + b), weights in LDS.
// deg = row_ptr[n+1]-row_ptr[n].  ACT: 0 = relu, 1 = sigmoid
template <int CI, int CO, int CO_TILE, int ACT>
__global__ void combine_kernel(const float* __restrict__ h, const float* __restrict__ agg,
                               const int* __restrict__ row_ptr,
                               const float* __restrict__ Ws, const float* __restrict__ Wn,
                               const float* __restrict__ bias,
                               float* __restrict__ out, int N) {
    constexpr int GP = CO_TILE / 4;
    extern __shared__ float lds[];
    float* sWs = lds;                // [CI][CO_TILE]
    float* sWn = lds + CI * CO_TILE; // [CI][CO_TILE]
    const int j0 = blockIdx.y * CO_TILE;
    for (int i = threadIdx.x; i < CI * CO_TILE; i += blockDim.x) {
        int k = i / CO_TILE;
        int j = i - k * CO_TILE;
        sWs[i] = Ws[(size_t)k * CO + j0 + j];
        sWn[i] = Wn[(size_t)k * CO + j0 + j];
    }
    __syncthreads();

    int t = blockIdx.x * blockDim.x + threadIdx.x;
    int total = N * GP;
    if (t >= total) return;
    int n = t / GP;
    int g = t - n * GP;

    float degf = (float)(row_ptr[n + 1] - row_ptr[n]);
    float inv = 1.0f / fmaxf(degf, 1.0f);
    float4 acc = *(const float4*)(bias + j0 + g * 4);
    const float* hr = h + (size_t)n * CI;
    const float* ar = agg + (size_t)n * CI;
#pragma unroll
    for (int k = 0; k < CI; k++) {
        float hv = hr[k];
        float av = ar[k] * inv;
        float4 ws = *(const float4*)(sWs + k * CO_TILE + g * 4);
        float4 wn = *(const float4*)(sWn + k * CO_TILE + g * 4);
        acc.x += hv * ws.x + av * wn.x;
        acc.y += hv * ws.y + av * wn.y;
        acc.z += hv * ws.z + av * wn.z;
        acc.w += hv * ws.w + av * wn.w;
    }
    if (ACT == 0) {
        acc.x = fmaxf(acc.x, 0.0f);
        acc.y = fmaxf(acc.y, 0.0f);
        acc.z = fmaxf(acc.z, 0.0f);
        acc.w = fmaxf(acc.w, 0.0f);
    } else {
        acc.x = 1.0f / (1.0f + __expf(-acc.x));
        acc.y = 1.0f / (1.0f + __expf(-acc.y));
        acc.z = 1.0f / (1.0f + __expf(-acc.z));
        acc.w = 1.0f / (1.0f + __expf(-acc.w));
    }
    *(float4*)(out + (size_t)n * CO + j0 + g * 4) = acc;
}

extern "C" void kernel_launch(void* const* d_in, const int* in_sizes, int n_in,
                              void* d_out, int out_size, void* d_ws, size_t ws_size,
                              hipStream_t stream) {
    const float* x     = (const float*)d_in[0];
    const int*   ei    = (const int*)d_in[1];
    // d_in[2]: batch (unused)
    const float* W_lin = (const float*)d_in[3];
    const float* b_lin = (const float*)d_in[4];
    const float* Ws3   = (const float*)d_in[5];
    const float* Wn3   = (const float*)d_in[6];
    const float* b3    = (const float*)d_in[7];
    const float* Ws2   = (const float*)d_in[8];
    const float* Wn2   = (const float*)d_in[9];
    const float* b2    = (const float*)d_in[10];
    const float* Ws1   = (const float*)d_in[11];
    const float* Wn1   = (const float*)d_in[12];
    const float* b1    = (const float*)d_in[13];
    float* out = (float*)d_out;

    const int N = in_sizes[0] / 16;
    const int E = in_sizes[1] / 2;
    const int* src = ei;
    const int* dst = ei + E;
    const int NB = (N + 255) / 256;   // scan blocks (512 for N=131072)

    // Workspace layout (4-byte elements). Peak ~76.5 MB.
    //   row_ptr : [0, N+1)
    //   cnt/cursor: [N+1, 2N+1)
    //   bsum    : [2N+1, 2N+1+NB)
    //   csr_src : [A, A+E)            A = align4(2N+1+NB)
    //   pool P  = align4(A+E):
    //     h0    : P        .. P+16N
    //     agg16 : P+16N    .. P+32N
    //     h3    : P+32N    .. P+64N
    //     agg32 = P (reuses h0+agg16)
    //     h2    : P+64N    .. P+128N
    //     agg64 = P (reuses h0..h3)
    int* wsi = (int*)d_ws;
    int* row_ptr = wsi;
    int* cnt     = wsi + (N + 1);          // doubles as cursor
    int* bsum    = wsi + (2 * N + 1);
    size_t A = (size_t)(2 * N + 1 + NB + 3) & ~(size_t)3;
    int* csr_src = wsi + A;
    size_t P = (A + (size_t)E + 3) & ~(size_t)3;
    float* h0    = (float*)(wsi + P);
    float* agg16 = h0 + (size_t)16 * N;
    float* h3    = h0 + (size_t)32 * N;
    float* agg32 = h0;
    float* h2    = h0 + (size_t)64 * N;
    float* agg64 = h0;

    const int BLK = 256;

    // ---- CSR build (int atomics only) ----
    hipMemsetAsync(cnt, 0, (size_t)N * 4, stream);
    hist_kernel<<<(E + BLK - 1) / BLK, BLK, 0, stream>>>(dst, cnt, E);
    scan1_kernel<<<NB, 256, 0, stream>>>(cnt, row_ptr, bsum);
    scan2_kernel<<<1, NB, NB * sizeof(int), stream>>>(bsum, NB);
    scan3_kernel<<<NB, 256, 0, stream>>>(row_ptr, bsum, N, E);
    hipMemsetAsync(cnt, 0, (size_t)N * 4, stream);   // cursor = 0
    fill_kernel<<<(E + BLK - 1) / BLK, BLK, 0, stream>>>(src, dst, row_ptr, cnt, csr_src, E);

    // ---- h0 = x @ W_lin + b_lin ----
    lin16_kernel<<<(N + BLK - 1) / BLK, BLK, 0, stream>>>(x, W_lin, b_lin, h0, N);

    // ---- block3: 16 -> 32, relu ----
    gather_kernel<16><<<((size_t)N * 4 + BLK - 1) / BLK, BLK, 0, stream>>>(row_ptr, csr_src, h0, agg16, N);
    {
        dim3 grid((N * 8 + BLK - 1) / BLK, 1);
        size_t shmem = 2 * 16 * 32 * sizeof(float);
        combine_kernel<16, 32, 32, 0><<<grid, BLK, shmem, stream>>>(h0, agg16, row_ptr, Ws3, Wn3, b3, h3, N);
    }

    // ---- block2: 32 -> 64, relu ----
    gather_kernel<32><<<((size_t)N * 8 + BLK - 1) / BLK, BLK, 0, stream>>>(row_ptr, csr_src, h3, agg32, N);
    {
        dim3 grid((N * 16 + BLK - 1) / BLK, 1);
        size_t shmem = 2 * 32 * 64 * sizeof(float);
        combine_kernel<32, 64, 64, 0><<<grid, BLK, shmem, stream>>>(h3, agg32, row_ptr, Ws2, Wn2, b2, h2, N);
    }

    // ---- block1: 64 -> 128, sigmoid -> d_out ----
    gather_kernel<64><<<((size_t)N * 16 + BLK - 1) / BLK, BLK, 0, stream>>>(row_ptr, csr_src, h2, agg64, N);
    {
        dim3 grid((N * 16 + BLK - 1) / BLK, 2);
        size_t shmem = 2 * 64 * 64 * sizeof(float);
        combine_kernel<64, 128, 64, 1><<<grid, BLK, shmem, stream>>>(h2, agg64, row_ptr, Ws1, Wn1, b1, out, N);
    }
}